// Round 19
// baseline (4379.860 us; speedup 1.0000x reference)
//
#include <hip/hip_runtime.h>
#include <math.h>

#define B 16
#define S 32
#define T 64
#define H2 512
#define Hf 256
#define F 128
#define A 128
#define V 32000
#define SW 1024
#define NSTEP 63
#define VP1 32001
#define NBLK 256

__device__ __forceinline__ float frcp(float x){ return __builtin_amdgcn_rcpf(x); }
__device__ __forceinline__ float fsigm(float x){ return frcp(1.f + __expf(-x)); }
__device__ __forceinline__ float ftanh_(float x){
    float e = __expf(-2.f*fabsf(x));
    float t = (1.f - e)*frcp(1.f + e);
    return x >= 0.f ? t : -t;
}
__device__ __forceinline__ void ast(float* p, float v){
    __hip_atomic_store(p, v, __ATOMIC_RELAXED, __HIP_MEMORY_SCOPE_AGENT);
}
__device__ __forceinline__ void astu(unsigned* p, unsigned v){
    __hip_atomic_store(p, v, __ATOMIC_RELAXED, __HIP_MEMORY_SCOPE_AGENT);
}
__device__ __forceinline__ unsigned bfr(float x){
    unsigned u = __float_as_uint(x);
    return (u + 0x7fffu + ((u >> 16) & 1u)) >> 16;
}
__device__ __forceinline__ float blo(unsigned u){ return __uint_as_float(u << 16); }
__device__ __forceinline__ float bhi(unsigned u){ return __uint_as_float(u & 0xffff0000u); }

// grid barrier: RMW-free leader-poll, 8x replicated release (R17 proven-best)
__device__ __forceinline__ void gbar(unsigned* arr, unsigned* rel, unsigned gen){
    asm volatile("s_waitcnt vmcnt(0) lgkmcnt(0)" ::: "memory");
    __syncthreads();
    if (blockIdx.x == 0){
        if (threadIdx.x > 0 && threadIdx.x < NBLK){
            while (__hip_atomic_load(&arr[threadIdx.x*32], __ATOMIC_RELAXED,
                                     __HIP_MEMORY_SCOPE_AGENT) < gen)
                __builtin_amdgcn_s_sleep(1);
        }
        __syncthreads();
        if (threadIdx.x < 8)
            __hip_atomic_store(&rel[threadIdx.x*32], gen, __ATOMIC_RELAXED,
                               __HIP_MEMORY_SCOPE_AGENT);
        __syncthreads();
    } else {
        if (threadIdx.x == 0){
            __hip_atomic_store(&arr[blockIdx.x*32], gen, __ATOMIC_RELAXED,
                               __HIP_MEMORY_SCOPE_AGENT);
            while (__hip_atomic_load(&rel[(blockIdx.x & 7)*32], __ATOMIC_RELAXED,
                                     __HIP_MEMORY_SCOPE_AGENT) < gen)
                __builtin_amdgcn_s_sleep(1);
        }
        __syncthreads();
    }
}

// ---------------- init ----------------
__global__ __launch_bounds__(256) void k_init0(
    const float* __restrict__ emb, const float* __restrict__ W_cc,
    const float* __restrict__ b_cc, const int* __restrict__ summary,
    float* __restrict__ xR, unsigned* __restrict__ cnt)
{
    int blk = blockIdx.x, tid = threadIdx.x;
    if (blk < 16){
        int b = blk;
        int tok = summary[b*T + 0];
        if (tid < F){
            float a = 0.f;
            for (int k = 0; k < F; ++k) a += emb[(size_t)tok*F + k]*W_cc[(size_t)k*F + tid];
            xR[b*F + tid] = a + b_cc[tid];
        }
    } else {
        for (int i = tid; i < 8704; i += 256) cnt[i] = 0u;
    }
}

// ---------------- precompute ws_aT[b][a][n] ----------------
__global__ __launch_bounds__(256) void k_wsa(
    const float* __restrict__ ws, const float* __restrict__ W_a, const float* __restrict__ b_a,
    float* __restrict__ ws_aT)
{
    __shared__ float wss2[512][20];
    int b = blockIdx.x, nt = blockIdx.y, tid = threadIdx.x;
    int n0 = nt*16;
    const float* wsrc = ws + ((size_t)(b*SW + n0))*H2;
    for (int i = tid; i < 16*512; i += 256){
        int n_l = i >> 9, k = i & 511;
        wss2[k][n_l] = wsrc[i];
    }
    __syncthreads();
    int a = tid & 127, nh = tid >> 7;
    float acc[8];
    float ba = b_a[a];
    #pragma unroll
    for (int j = 0; j < 8; ++j) acc[j] = ba;
    for (int k = 0; k < H2; ++k){
        float wa = W_a[k*A + a];
        const float4 u0 = *(const float4*)&wss2[k][nh*8];
        const float4 u1 = *(const float4*)&wss2[k][nh*8 + 4];
        acc[0] += u0.x*wa; acc[1] += u0.y*wa; acc[2] += u0.z*wa; acc[3] += u0.w*wa;
        acc[4] += u1.x*wa; acc[5] += u1.y*wa; acc[6] += u1.z*wa; acc[7] += u1.w*wa;
    }
    float* dst = ws_aT + ((size_t)(b*A + a))*SW + n0 + nh*8;
    #pragma unroll
    for (int j = 0; j < 8; ++j) dst[j] = acc[j];
}

// ---------------- Wf = W_rc @ W1_top ; bf ; bconst ----------------
__global__ __launch_bounds__(256) void k_wf(
    const float* __restrict__ W_rc, const float* __restrict__ b_rc,
    const float* __restrict__ W1, const float* __restrict__ b1,
    const float* __restrict__ W_cc,
    float* __restrict__ Wf, float* __restrict__ bf, float* __restrict__ bconst)
{
    __shared__ float wrc[4][512];
    int j = blockIdx.x, tid = threadIdx.x;
    if (j < 256){
        for (int i = tid; i < 2048; i += 256){
            int kk = i >> 9, r = i & 511;
            wrc[kk][r] = W_rc[((size_t)(j*4 + kk))*H2 + r];
        }
        __syncthreads();
        float a0=0,a1=0,a2=0,a3=0;
        for (int r = 0; r < 512; ++r){
            float w1 = W1[(size_t)r*Hf + tid];
            a0 += wrc[0][r]*w1; a1 += wrc[1][r]*w1; a2 += wrc[2][r]*w1; a3 += wrc[3][r]*w1;
        }
        Wf[((size_t)(j*4+0))*Hf + tid] = a0;
        Wf[((size_t)(j*4+1))*Hf + tid] = a1;
        Wf[((size_t)(j*4+2))*Hf + tid] = a2;
        Wf[((size_t)(j*4+3))*Hf + tid] = a3;
    } else {
        float acc = b1[tid];
        for (int r = 0; r < 512; ++r) acc += b_rc[r]*W1[(size_t)r*Hf + tid];
        bf[tid] = acc;
        if (tid < 128){
            float a = 0.f;
            for (int c = 0; c < H2; ++c) a += b_rc[c]*W_cc[(size_t)(F+c)*F + tid];
            bconst[tid] = a;
        }
    }
}

// ---------------- WRCC = W_rc @ W_cc_bot ----------------
__global__ __launch_bounds__(128) void k_wrcc(
    const float* __restrict__ W_rc, const float* __restrict__ W_cc, float* __restrict__ WRCC)
{
    __shared__ float wr[512];
    int d = blockIdx.x, f = threadIdx.x;
    for (int i = f; i < 512; i += 128) wr[i] = W_rc[(size_t)d*H2 + i];
    __syncthreads();
    float a = 0.f;
    for (int c = 0; c < H2; ++c) a += wr[c]*W_cc[(size_t)(F+c)*F + f];
    WRCC[(size_t)d*F + f] = a;
}

// ---------------- embx ----------------
__global__ __launch_bounds__(128) void k_embx(
    const int* __restrict__ summary, const float* __restrict__ emb,
    const float* __restrict__ W_cc, const float* __restrict__ b_cc,
    float* __restrict__ embx)
{
    __shared__ float er[128];
    int t = blockIdx.x, b = blockIdx.y, f = threadIdx.x;
    int tok = summary[b*T + t];
    er[f] = emb[(size_t)tok*F + f];
    __syncthreads();
    float a = b_cc[f];
    for (int k = 0; k < F; ++k) a += er[k]*W_cc[(size_t)k*F + f];
    embx[((size_t)t*B + b)*F + f] = a;
}

// ---------------- bf16 pack kernels ----------------
__global__ __launch_bounds__(1024) void k_packw2(
    const float* __restrict__ W2, unsigned* __restrict__ W2h)
{
    size_t idx = (size_t)blockIdx.x*1024 + threadIdx.x;
    int rp = (int)(idx >> 15), v = (int)(idx & 32767);
    float lo = (v < VP1) ? W2[(size_t)(2*rp)*VP1 + v] : 0.f;
    float hi = (v < VP1) ? W2[(size_t)(2*rp+1)*VP1 + v] : 0.f;
    W2h[idx] = bfr(lo) | (bfr(hi) << 16);
}
__global__ __launch_bounds__(1024) void k_packws(
    const float* __restrict__ ws, unsigned* __restrict__ wsh)
{
    size_t idx = (size_t)blockIdx.x*1024 + threadIdx.x;
    int b = (int)(idx >> 18), r = (int)(idx & 262143);
    int np = r >> 9, d = r & 511;
    float lo = ws[((size_t)b*SW + 2*np)*H2 + d];
    float hi = ws[((size_t)b*SW + 2*np+1)*H2 + d];
    wsh[idx] = bfr(lo) | (bfr(hi) << 16);
}
__global__ __launch_bounds__(1024) void k_packwsa(
    const float* __restrict__ ws_aT, unsigned* __restrict__ ws_aTh)
{
    size_t idx = (size_t)blockIdx.x*1024 + threadIdx.x;
    int b = (int)(idx >> 16), r = (int)(idx & 65535);
    int ap = r >> 10, n = r & 1023;
    float lo = ws_aT[((size_t)b*A + 2*ap)*SW + n];
    float hi = ws_aT[((size_t)b*A + 2*ap+1)*SW + n];
    ws_aTh[idx] = bfr(lo) | (bfr(hi) << 16);
}
__global__ __launch_bounds__(1024) void k_packwg(
    const float* __restrict__ Wx, const float* __restrict__ Wh,
    unsigned* __restrict__ wgh)
{
    size_t idx = (size_t)blockIdx.x*1024 + threadIdx.x;
    int kp = (int)(idx >> 11), cg = (int)(idx & 2047);
    int k0 = 2*kp, k1 = 2*kp + 1;
    float lo = (k0 < F) ? Wx[(size_t)k0*2048 + cg] : Wh[(size_t)(k0-F)*2048 + cg];
    float hi = (k1 < F) ? Wx[(size_t)k1*2048 + cg] : Wh[(size_t)(k1-F)*2048 + cg];
    wgh[idx] = bfr(lo) | (bfr(hi) << 16);
}

// ---------------- persistent time-loop kernel (512 threads, 3 barriers/step) ----------------
__global__ __launch_bounds__(512, 2) void k_persist(
    const float* __restrict__ ss,
    const int* __restrict__ text_length, const int* __restrict__ summary,
    const int* __restrict__ sumlen, const float* __restrict__ state,
    const unsigned* __restrict__ wgh, const float* __restrict__ b_lstm,
    const float* __restrict__ W_a, const float* __restrict__ v_a,
    const float* __restrict__ W1, const float* __restrict__ b2,
    const unsigned* __restrict__ W2h, const unsigned* __restrict__ wsh,
    const unsigned* __restrict__ ws_aTh,
    const float* __restrict__ Wf, const float* __restrict__ bf,
    const float* __restrict__ WRCC, const float* __restrict__ bconst,
    const float* __restrict__ embx,
    float* xR, float* outR, float* hidR,
    unsigned* wopartH, unsigned* PpkR, float* ZpartR, float* asumR,
    float* m2R, float* s2R, float* tgtlogR, float* covlpR,
    float* d_out, unsigned* cnt)
{
    __shared__ unsigned W2L[16384];   // 64 KB
    __shared__ unsigned wsaL[4096];   // 16 KB
    __shared__ float BIG[15552];
    __shared__ float redS[576];
    __shared__ float red2[528];
    __shared__ float wo_l[128];
    __shared__ float wac_l[128], vas_l[128], b2_l[128];
    __shared__ float expU_l[64], cov_l[64];
    __shared__ float c_l[128];
    __shared__ float gsum[528];
    __shared__ float asum_l[32];
    __shared__ float mred[136], sred[136], msc2[16];
    __shared__ float loss_l[16];
    __shared__ float Zsh;
    __shared__ int tl_l[32], sumlen_l[16], tgt_l[16];

    const int blk = blockIdx.x, tid = threadIdx.x;
    const int b_role = blk >> 4, sl = blk & 15;
    unsigned* arr = cnt;
    unsigned* rel = cnt + 8192;

    const int vl = tid & 127, rq = tid >> 7;        // logits
    const int n3 = tid & 63, aq = tid >> 6;         // scores
    const int cc = tid & 31, kg = tid >> 5;         // gates

    unsigned wsrN[32];
    #pragma unroll
    for (int j = 0; j < 32; ++j)
        wsrN[j] = wsh[((size_t)b_role*512 + sl*32 + j)*512 + tid];
    unsigned wgr[20];
    if (blk < 64){
        const int CGg = (cc >> 3)*512 + blk*8 + (cc & 7);
        #pragma unroll
        for (int j = 0; j < 20; ++j)
            wgr[j] = wgh[(size_t)(kg*20 + j)*2048 + CGg];
    }
    #pragma unroll
    for (int q = 0; q < 32; ++q){
        int i = q*512 + tid;
        W2L[i] = W2h[(size_t)(i >> 7)*32768 + blk*128 + (i & 127)];
    }
    #pragma unroll
    for (int q = 0; q < 8; ++q){
        int i = q*512 + tid;
        wsaL[i] = ws_aTh[((size_t)(b_role*64 + (i >> 6)))*1024 + sl*64 + (i & 63)];
    }

    if (tid < 128){
        wac_l[tid] = W_a[(size_t)(2*H2)*A + tid];
        vas_l[tid] = v_a[tid];
        int v2 = blk*128 + tid;
        b2_l[tid] = (v2 < VP1) ? b2[v2] : 0.f;
    }
    if (tid < 32) tl_l[tid] = text_length[b_role*S + tid];
    if (tid < 16){ sumlen_l[tid] = sumlen[tid]; loss_l[tid] = 0.f; }
    if (tid < 64) cov_l[tid] = 0.f;
    if (blk < 64 && tid < 128){
        int b = tid >> 3, c = tid & 7;
        c_l[tid] = state[(size_t)b*2*H2 + H2 + blk*8 + c];
    }
    __syncthreads();

    unsigned gen = 0;
    for (int t = 0; t <= NSTEP; ++t){
        // ======== Phase A: cov/covloss(t-1) ; loss-merge(t-2) [blk255] ; gates(t) [blk<64] ========
        if (t >= 1){
            float invZ = frcp(Zsh);
            if (tid < 64){
                float at = expU_l[tid]*invZ;
                float clp = fminf(cov_l[tid], at);
                float vm1 = (sumlen_l[b_role] - t > 0) ? 1.f : 0.f;
                cov_l[tid] += at*vm1;
                float s = clp;
                s += __shfl_xor(s, 1);  s += __shfl_xor(s, 2);
                s += __shfl_xor(s, 4);  s += __shfl_xor(s, 8);
                s += __shfl_xor(s, 16); s += __shfl_xor(s, 32);
                if (tid == 0) ast(&covlpR[(size_t)(t-1)*256 + b_role*16 + sl], s);
            }
        }
        if (t >= 2 && blk == 255 && tid < 256){
            int tf = t - 2;
            int bb = tid >> 4, g = tid & 15;
            float mv[16];
            float m = -1e30f;
            #pragma unroll
            for (int j = 0; j < 16; ++j){
                mv[j] = m2R[(size_t)tf*B*256 + bb*256 + g + j*16];
                m = fmaxf(m, mv[j]);
            }
            #pragma unroll
            for (int off = 1; off < 16; off <<= 1) m = fmaxf(m, __shfl_xor(m, off, 16));
            float s = 0.f;
            #pragma unroll
            for (int j = 0; j < 16; ++j)
                s += s2R[(size_t)tf*B*256 + bb*256 + g + j*16]*__expf(mv[j]-m);
            #pragma unroll
            for (int off = 1; off < 16; off <<= 1) s += __shfl_xor(s, off, 16);
            if (g == 0){
                float cl = 0.f;
                for (int q = 0; q < 16; ++q) cl += covlpR[(size_t)tf*256 + bb*16 + q];
                float tlg = tgtlogR[(size_t)tf*16 + bb];
                float logp = tlg - m - __logf(s);
                float vld = (sumlen_l[bb] - tf - 1 > 0) ? 1.f : 0.f;
                loss_l[bb] += vld*(-logp + cl);
            }
        }
        if (t < NSTEP && blk < 64){
            float* xh = BIG;
            float* outloc = BIG + 14336;
            float* waL = BIG + 14464;
            {
                int i2 = tid*2;
                waL[i2]   = W_a[(size_t)(H2 + blk*8 + (i2 >> 7))*A + (i2 & 127)];
                waL[i2+1] = W_a[(size_t)(H2 + blk*8 + ((i2+1) >> 7))*A + ((i2+1) & 127)];
            }
            const float* xb0 = xR + (size_t)t*B*F;
            const float* hb0 = outR + (size_t)(t > 0 ? t-1 : 0)*B*H2;
            #pragma unroll
            for (int q = 0; q < 20; ++q){
                int i = q*512 + tid;
                int b = i/640, k = i - b*640;
                float v;
                if (k < F) v = xb0[b*F + k];
                else if (t == 0) v = state[(size_t)b*2*H2 + (k - F)];
                else v = hb0[b*H2 + (k - F)] * ((sumlen_l[b] - t > 0) ? 1.f : 0.f);
                xh[i] = v;
            }
            __syncthreads();
            for (int b = 0; b < 16; ++b){
                const float* xb = &BIG[b*640 + kg*40];
                float s0 = 0.f, s1 = 0.f;
                #pragma unroll
                for (int j = 0; j < 20; ++j){
                    unsigned wu = wgr[j];
                    s0 = fmaf(xb[2*j],   blo(wu), s0);
                    s1 = fmaf(xb[2*j+1], bhi(wu), s1);
                }
                float p = s0 + s1;
                p += __shfl_xor(p, 32);
                if ((kg & 1) == 0)
                    BIG[10240 + (b*8 + (kg >> 1))*32 + cc] = p;
            }
            __syncthreads();
            {
                int b = tid >> 5, c2 = tid & 31;
                float s = 0.f;
                #pragma unroll
                for (int q = 0; q < 8; ++q) s += BIG[10240 + (b*8 + q)*32 + c2];
                gsum[b*33 + c2] = s;
            }
            __syncthreads();
            if (tid < 128){
                int b = tid >> 3, c = tid & 7, col = blk*8 + c;
                float gi = gsum[b*33 + c]      + b_lstm[col];
                float gf = gsum[b*33 + 8 + c]  + b_lstm[H2 + col];
                float gg = gsum[b*33 + 16 + c] + b_lstm[2*H2 + col];
                float go = gsum[b*33 + 24 + c] + b_lstm[3*H2 + col];
                float cold = c_l[tid];
                float cn = fsigm(gf)*cold + fsigm(gi)*ftanh_(gg);
                float o = fsigm(go)*ftanh_(cn);
                float valid = (sumlen_l[b] - t - 1 > 0) ? 1.f : 0.f;
                c_l[tid] = cn*valid;
                outloc[tid] = o;
                ast(&outR[(size_t)t*B*H2 + b*H2 + col], o);
            }
            __syncthreads();
            {
                int o2 = tid*2;
                int b = o2 >> 6, ap0 = o2 & 63;
                #pragma unroll
                for (int w = 0; w < 2; ++w){
                    int ap = ap0 + w, a0 = ap*2;
                    float acc0 = 0.f, acc1 = 0.f;
                    #pragma unroll
                    for (int j = 0; j < 8; ++j){
                        float ov = outloc[b*8 + j];
                        acc0 = fmaf(ov, waL[j*128 + a0],     acc0);
                        acc1 = fmaf(ov, waL[j*128 + a0 + 1], acc1);
                    }
                    astu(&wopartH[(size_t)t*65536 + blk*1024 + b*64 + ap],
                         bfr(acc0) | (bfr(acc1) << 16));
                }
            }
        }
        gen++; gbar(arr, rel, gen);

        // ======== Phase B: hidL prefetch (t>=1) ; wo-reduce + scores + P (t<NSTEP) ========
        if (t >= 1){
            float* hidL = BIG + 2560;
            if (tid < 16){ int tok = summary[tid*T + t]; tgt_l[tid] = (tok == -1) ? V : tok; }
            #pragma unroll
            for (int q = 0; q < 8; ++q){
                int idx = q*512 + tid;
                int r = idx >> 4, b = idx & 15;
                hidL[b*264 + r] = hidR[(size_t)(t-1)*B*Hf + idx];
            }
        }
        if (t < NSTEP){
            gsum[tid] = outR[(size_t)t*B*H2 + b_role*H2 + tid];
            {
                int ap = tid & 63, grp = tid >> 6;
                const unsigned* wp = wopartH + (size_t)t*65536 + (size_t)(grp*8)*1024
                                     + b_role*64 + ap;
                float lo = 0.f, hi = 0.f;
                #pragma unroll
                for (int q = 0; q < 8; ++q){
                    unsigned u = wp[(size_t)q*1024];
                    lo += blo(u); hi += bhi(u);
                }
                red2[ap*8 + grp] = lo;
                redS[ap*8 + grp] = hi;
            }
            __syncthreads();
            if (tid < 64){
                float lo = 0.f, hi = 0.f;
                #pragma unroll
                for (int q = 0; q < 8; ++q){ lo += red2[tid*8+q]; hi += redS[tid*8+q]; }
                wo_l[tid*2] = lo; wo_l[tid*2+1] = hi;
            }
            __syncthreads();
            {
                float cv = cov_l[n3];
                float acc = 0.f;
                #pragma unroll
                for (int i = 0; i < 8; ++i){
                    unsigned u = wsaL[(aq*8 + i)*64 + n3];
                    int a0 = aq*16 + 2*i;
                    acc = fmaf(ftanh_(blo(u) + wo_l[a0] + cv*wac_l[a0]), vas_l[a0], acc);
                    acc = fmaf(ftanh_(bhi(u) + wo_l[a0+1] + cv*wac_l[a0+1]), vas_l[a0+1], acc);
                }
                redS[aq*72 + n3] = acc;
            }
            __syncthreads();
            if (tid < 64){
                float s = 0.f;
                #pragma unroll
                for (int q = 0; q < 8; ++q) s += redS[q*72 + tid];
                int nn = sl*64 + tid;
                float sc = ((nn & 31) < tl_l[nn >> 5]) ? s : -1e9f;
                float e = __expf(sc);
                expU_l[tid] = e;
                float h = e;
                h += __shfl_xor(h, 1);  h += __shfl_xor(h, 2);
                h += __shfl_xor(h, 4);  h += __shfl_xor(h, 8);
                h += __shfl_xor(h, 16);
                float other = __shfl_xor(h, 32);
                if (tid == 0){
                    ast(&asumR[(size_t)t*512 + b_role*32 + sl*2 + 0], h);
                    ast(&asumR[(size_t)t*512 + b_role*32 + sl*2 + 1], other);
                    ast(&ZpartR[(size_t)t*256 + b_role*16 + sl], h + other);
                }
            }
            __syncthreads();
            {
                float p = 0.f;
                #pragma unroll
                for (int j = 0; j < 32; ++j){
                    unsigned u = wsrN[j];
                    p = fmaf(expU_l[2*j],   blo(u), p);
                    p = fmaf(expU_l[2*j+1], bhi(u), p);
                }
                float pnb = __shfl_xor(p, 1);
                if (!(tid & 1))
                    astu(&PpkR[((size_t)t*256 + blk)*256 + (tid >> 1)],
                         bfr(p) | (bfr(pnb) << 16));
            }
        }
        gen++; gbar(arr, rel, gen);

        // ======== Phase C: combine->c4 + hid/x (t<NSTEP) ; logits(t-1) (t>=1) ========
        {
            float* c4l  = BIG;            // [0,1024)
            float* OL   = gsum;           // prefetched in B
            float* redd = BIG + 1536;     // [1536,2048)
            float* hidL = BIG + 2560;     // prefetched in B
            float* parts = BIG + 6784;    // [6784,15488)
            float* logitl = parts;
            if (t < NSTEP){
                if (tid < 16) mred[tid] = ZpartR[(size_t)t*256 + b_role*16 + tid];
                if (tid >= 32 && tid < 64) asum_l[tid-32] = asumR[(size_t)t*512 + b_role*32 + (tid-32)];
                if (tid < 256){
                    float lo = 0.f, hi = 0.f;
                    const unsigned* pp = PpkR + ((size_t)t*256 + b_role*16)*256 + tid;
                    #pragma unroll
                    for (int q = 0; q < 16; ++q){
                        unsigned u = pp[(size_t)q*256];
                        lo += blo(u); hi += bhi(u);
                    }
                    c4l[2*tid] = lo; c4l[2*tid+1] = hi;
                }
            }
            __syncthreads();
            if (t < NSTEP){
                float zloc = 0.f;
                #pragma unroll
                for (int i = 0; i < 16; ++i) zloc += mred[i];
                if (tid == 0) Zsh = zloc;
                float invZ = frcp(zloc);
                float sent = 0.f;
                const float* ssb = ss + (size_t)(b_role*S)*H2 + tid;
                #pragma unroll 4
                for (int s2 = 0; s2 < 32; ++s2)
                    sent = fmaf(asum_l[s2], ssb[(size_t)s2*H2], sent);
                float w = c4l[tid]*invZ;
                c4l[tid] = w;
                c4l[512 + tid] = sent*invZ;
            }
            __syncthreads();
            if (t >= 1){
                unsigned wreg[32];
                #pragma unroll
                for (int i = 0; i < 32; ++i) wreg[i] = W2L[(rq*32 + i)*128 + vl];
                for (int b = 0; b < 16; ++b){
                    const float2* hb2 = (const float2*)&hidL[b*264 + rq*64];
                    float a0 = 0.f, a1 = 0.f;
                    #pragma unroll
                    for (int i = 0; i < 32; ++i){
                        unsigned u = wreg[i];
                        float2 h = hb2[i];
                        a0 = fmaf(h.x, blo(u), a0);
                        a1 = fmaf(h.y, bhi(u), a1);
                    }
                    parts[rq*2176 + vl*17 + b] = a0 + a1;
                }
            }
            if (t < NSTEP && sl < 12){
                int cl = tid & 31, kq = tid >> 5;
                if (sl < 8){
                    int col = sl*32 + cl;
                    float acc = 0.f;
                    const float* wp = Wf + (size_t)(kq*64)*Hf + col;
                    #pragma unroll 4
                    for (int i = 0; i < 64; ++i)
                        acc = fmaf(c4l[kq*64+i], wp[(size_t)i*Hf], acc);
                    const float* w1p = W1 + (size_t)(H2 + kq*32)*Hf + col;
                    #pragma unroll 4
                    for (int i = 0; i < 32; ++i)
                        acc = fmaf(OL[kq*32+i], w1p[(size_t)i*Hf], acc);
                    redd[kq*32 + cl] = acc;
                } else {
                    int f = (sl-8)*32 + cl;
                    float acc = 0.f;
                    const float* wp = WRCC + (size_t)(kq*64)*F + f;
                    #pragma unroll 4
                    for (int i = 0; i < 64; ++i)
                        acc = fmaf(c4l[kq*64+i], wp[(size_t)i*F], acc);
                    redd[kq*32 + cl] = acc;
                }
            }
            __syncthreads();
            if (t < NSTEP && sl < 12 && tid < 32){
                if (sl < 8){
                    float z = 0.f;
                    #pragma unroll
                    for (int q = 0; q < 16; ++q) z += redd[q*32 + tid];
                    z += bf[sl*32 + tid];
                    ast(&hidR[(size_t)t*B*Hf + (sl*32 + tid)*16 + b_role], fmaxf(z, 0.f));
                } else {
                    int f2 = (sl-8)*32 + tid;
                    float z = 0.f;
                    #pragma unroll
                    for (int q = 0; q < 16; ++q) z += redd[q*32 + tid];
                    float vld = (sumlen_l[b_role] - t - 1 > 0) ? 1.f : 0.f;
                    float xv = embx[((size_t)(t+1)*B + b_role)*F + f2] + vld*(z + bconst[f2]);
                    ast(&xR[(size_t)(t+1)*B*F + b_role*F + f2], xv);
                }
            }
            if (t >= 1){
                #pragma unroll
                for (int j = 0; j < 4; ++j){
                    int idx = tid*4 + j;
                    int vl2 = idx >> 4, bb = idx & 15;
                    float s = parts[0*2176 + vl2*17 + bb]
                            + parts[1*2176 + vl2*17 + bb]
                            + parts[2*2176 + vl2*17 + bb]
                            + parts[3*2176 + vl2*17 + bb];
                    int v2 = blk*128 + vl2;
                    float lg = (v2 < VP1) ? (s + b2_l[vl2]) : -1e30f;
                    if (v2 < VP1 && v2 == tgt_l[bb])
                        ast(&tgtlogR[(size_t)(t-1)*16 + bb], lg);
                    logitl[vl2*17 + bb] = lg;
                }
                __syncthreads();
                if (tid < 128){
                    int b2i = tid & 15, grp = tid >> 4;
                    float m = -1e30f;
                    #pragma unroll
                    for (int i = 0; i < 16; ++i) m = fmaxf(m, logitl[(grp*16+i)*17 + b2i]);
                    mred[grp*17 + b2i] = m;
                }
                __syncthreads();
                if (tid < 16){
                    float m = -1e30f;
                    #pragma unroll
                    for (int q = 0; q < 8; ++q) m = fmaxf(m, mred[q*17 + tid]);
                    msc2[tid] = m;
                }
                __syncthreads();
                if (tid < 128){
                    int b2i = tid & 15, grp = tid >> 4;
                    float Mb = msc2[b2i];
                    float s = 0.f;
                    #pragma unroll
                    for (int i = 0; i < 16; ++i) s += __expf(logitl[(grp*16+i)*17 + b2i] - Mb);
                    sred[grp*17 + b2i] = s;
                }
                __syncthreads();
                if (tid < 16){
                    float s = 0.f;
                    #pragma unroll
                    for (int q = 0; q < 8; ++q) s += sred[q*17 + tid];
                    ast(&m2R[(size_t)(t-1)*B*256 + tid*256 + blk], msc2[tid]);
                    ast(&s2R[(size_t)(t-1)*B*256 + tid*256 + blk], s);
                }
            }
        }
        gen++; gbar(arr, rel, gen);
    }

    // ======== epilogue: loss-merge(NSTEP-1) + output [blk255] ========
    if (blk == 255 && tid < 256){
        int tf = NSTEP - 1;
        int bb = tid >> 4, g = tid & 15;
        float mv[16];
        float m = -1e30f;
        #pragma unroll
        for (int j = 0; j < 16; ++j){
            mv[j] = m2R[(size_t)tf*B*256 + bb*256 + g + j*16];
            m = fmaxf(m, mv[j]);
        }
        #pragma unroll
        for (int off = 1; off < 16; off <<= 1) m = fmaxf(m, __shfl_xor(m, off, 16));
        float s = 0.f;
        #pragma unroll
        for (int j = 0; j < 16; ++j)
            s += s2R[(size_t)tf*B*256 + bb*256 + g + j*16]*__expf(mv[j]-m);
        #pragma unroll
        for (int off = 1; off < 16; off <<= 1) s += __shfl_xor(s, off, 16);
        if (g == 0){
            float cl = 0.f;
            for (int q = 0; q < 16; ++q) cl += covlpR[(size_t)tf*256 + bb*16 + q];
            float tlg = tgtlogR[(size_t)tf*16 + bb];
            float logp = tlg - m - __logf(s);
            float vld = (sumlen_l[bb] - tf - 1 > 0) ? 1.f : 0.f;
            loss_l[bb] += vld*(-logp + cl);
            d_out[bb] = loss_l[bb] / ((float)sumlen_l[bb] - 1.f);
        }
    }
}

extern "C" void kernel_launch(void* const* d_in, const int* in_sizes, int n_in,
                              void* d_out, int out_size, void* d_ws, size_t ws_size,
                              hipStream_t stream) {
    const float* text_states = (const float*)d_in[0];
    const float* sent_states = (const float*)d_in[1];
    const int*   text_length = (const int*)d_in[2];
    const float* state       = (const float*)d_in[3];
    const int*   summary     = (const int*)d_in[4];
    const int*   sumlen      = (const int*)d_in[5];
    const float* emb    = (const float*)d_in[6];
    const float* W_cc   = (const float*)d_in[7];
    const float* b_cc   = (const float*)d_in[8];
    const float* Wx     = (const float*)d_in[9];
    const float* Wh     = (const float*)d_in[10];
    const float* b_lstm = (const float*)d_in[11];
    const float* W_a    = (const float*)d_in[12];
    const float* b_a    = (const float*)d_in[13];
    const float* v_a    = (const float*)d_in[14];
    const float* W_rc   = (const float*)d_in[15];
    const float* b_rc   = (const float*)d_in[16];
    const float* W1     = (const float*)d_in[17];
    const float* b1     = (const float*)d_in[18];
    const float* W2     = (const float*)d_in[19];
    const float* b2     = (const float*)d_in[20];
    float* out = (float*)d_out;

    float* p = (float*)d_ws;
    float* ws_aT   = p; p += (size_t)B*A*SW;
    float* Wf      = p; p += (size_t)1024*Hf;
    float* bfv     = p; p += Hf;
    float* WRCC    = p; p += (size_t)1024*F;
    float* bconst  = p; p += F;
    float* embx    = p; p += (size_t)T*B*F;
    float* xR      = p; p += (size_t)(NSTEP+1)*B*F;
    float* outR    = p; p += (size_t)(NSTEP+1)*B*H2;
    float* hidR    = p; p += (size_t)(NSTEP+1)*B*Hf;
    float* ZpartR  = p; p += (size_t)(NSTEP+1)*256;
    float* asumR   = p; p += (size_t)(NSTEP+1)*512;
    float* m2R     = p; p += (size_t)(NSTEP+1)*B*256;
    float* s2R     = p; p += (size_t)(NSTEP+1)*B*256;
    float* tgtlogR = p; p += (size_t)(NSTEP+1)*16;
    float* covlpR  = p; p += (size_t)(NSTEP+1)*256;
    unsigned* cnt  = (unsigned*)p; p += 8704;
    unsigned* W2h    = (unsigned*)p; p += (size_t)128*32768;
    unsigned* wsh    = (unsigned*)p; p += (size_t)16*512*512;
    unsigned* ws_aTh = (unsigned*)p; p += (size_t)16*64*1024;
    unsigned* wgh    = (unsigned*)p; p += (size_t)320*2048;
    unsigned* wopartH= (unsigned*)p; p += (size_t)NSTEP*65536;
    unsigned* PpkR   = (unsigned*)p; p += (size_t)NSTEP*256*256;

    k_init0<<<17, 256, 0, stream>>>(emb, W_cc, b_cc, summary, xR, cnt);
    k_wsa<<<dim3(B, 64), 256, 0, stream>>>(text_states, W_a, b_a, ws_aT);
    k_wf<<<257, 256, 0, stream>>>(W_rc, b_rc, W1, b1, W_cc, Wf, bfv, bconst);
    k_wrcc<<<1024, 128, 0, stream>>>(W_rc, W_cc, WRCC);
    k_embx<<<dim3(T, B), 128, 0, stream>>>(summary, emb, W_cc, b_cc, embx);
    k_packw2<<<4096, 1024, 0, stream>>>(W2, W2h);
    k_packws<<<4096, 1024, 0, stream>>>(text_states, wsh);
    k_packwsa<<<1024, 1024, 0, stream>>>(ws_aT, ws_aTh);
    k_packwg<<<640, 1024, 0, stream>>>(Wx, Wh, wgh);
    k_persist<<<NBLK, 512, 0, stream>>>(
        sent_states, text_length, summary, sumlen, state,
        wgh, b_lstm, W_a, v_a, W1, b2,
        W2h, wsh, ws_aTh, Wf, bfv, WRCC, bconst, embx,
        xR, outR, hidR, wopartH, PpkR, ZpartR, asumR,
        m2R, s2R, tgtlogR, covlpR, out, cnt);
}

// Round 20
// 4082.644 us; speedup vs baseline: 1.0728x; 1.0728x over previous
//
#include <hip/hip_runtime.h>
#include <math.h>

#define B 16
#define S 32
#define T 64
#define H2 512
#define Hf 256
#define F 128
#define A 128
#define V 32000
#define SW 1024
#define NSTEP 63
#define VP1 32001
#define NBLK 256

__device__ __forceinline__ float frcp(float x){ return __builtin_amdgcn_rcpf(x); }
__device__ __forceinline__ float fsigm(float x){ return frcp(1.f + __expf(-x)); }
__device__ __forceinline__ float ftanh_(float x){
    float e = __expf(-2.f*fabsf(x));
    float t = (1.f - e)*frcp(1.f + e);
    return x >= 0.f ? t : -t;
}
__device__ __forceinline__ void ast(float* p, float v){
    __hip_atomic_store(p, v, __ATOMIC_RELAXED, __HIP_MEMORY_SCOPE_AGENT);
}
__device__ __forceinline__ void astu(unsigned* p, unsigned v){
    __hip_atomic_store(p, v, __ATOMIC_RELAXED, __HIP_MEMORY_SCOPE_AGENT);
}
__device__ __forceinline__ unsigned bfr(float x){
    unsigned u = __float_as_uint(x);
    return (u + 0x7fffu + ((u >> 16) & 1u)) >> 16;
}
__device__ __forceinline__ float blo(unsigned u){ return __uint_as_float(u << 16); }
__device__ __forceinline__ float bhi(unsigned u){ return __uint_as_float(u & 0xffff0000u); }

// grid barrier: RMW-free leader-poll, 8x replicated release (R17 proven-best)
__device__ __forceinline__ void gbar(unsigned* arr, unsigned* rel, unsigned gen){
    asm volatile("s_waitcnt vmcnt(0) lgkmcnt(0)" ::: "memory");
    __syncthreads();
    if (blockIdx.x == 0){
        if (threadIdx.x > 0 && threadIdx.x < NBLK){
            while (__hip_atomic_load(&arr[threadIdx.x*32], __ATOMIC_RELAXED,
                                     __HIP_MEMORY_SCOPE_AGENT) < gen)
                __builtin_amdgcn_s_sleep(1);
        }
        __syncthreads();
        if (threadIdx.x < 8)
            __hip_atomic_store(&rel[threadIdx.x*32], gen, __ATOMIC_RELAXED,
                               __HIP_MEMORY_SCOPE_AGENT);
        __syncthreads();
    } else {
        if (threadIdx.x == 0){
            __hip_atomic_store(&arr[blockIdx.x*32], gen, __ATOMIC_RELAXED,
                               __HIP_MEMORY_SCOPE_AGENT);
            while (__hip_atomic_load(&rel[(blockIdx.x & 7)*32], __ATOMIC_RELAXED,
                                     __HIP_MEMORY_SCOPE_AGENT) < gen)
                __builtin_amdgcn_s_sleep(1);
        }
        __syncthreads();
    }
}

// ---------------- init ----------------
__global__ __launch_bounds__(256) void k_init0(
    const float* __restrict__ emb, const float* __restrict__ W_cc,
    const float* __restrict__ b_cc, const int* __restrict__ summary,
    float* __restrict__ xR, unsigned* __restrict__ cnt)
{
    int blk = blockIdx.x, tid = threadIdx.x;
    if (blk < 16){
        int b = blk;
        int tok = summary[b*T + 0];
        if (tid < F){
            float a = 0.f;
            for (int k = 0; k < F; ++k) a += emb[(size_t)tok*F + k]*W_cc[(size_t)k*F + tid];
            xR[b*F + tid] = a + b_cc[tid];
        }
    } else {
        for (int i = tid; i < 8704; i += 256) cnt[i] = 0u;
    }
}

// ---------------- precompute ws_aT[b][a][n] ----------------
__global__ __launch_bounds__(256) void k_wsa(
    const float* __restrict__ ws, const float* __restrict__ W_a, const float* __restrict__ b_a,
    float* __restrict__ ws_aT)
{
    __shared__ float wss2[512][20];
    int b = blockIdx.x, nt = blockIdx.y, tid = threadIdx.x;
    int n0 = nt*16;
    const float* wsrc = ws + ((size_t)(b*SW + n0))*H2;
    for (int i = tid; i < 16*512; i += 256){
        int n_l = i >> 9, k = i & 511;
        wss2[k][n_l] = wsrc[i];
    }
    __syncthreads();
    int a = tid & 127, nh = tid >> 7;
    float acc[8];
    float ba = b_a[a];
    #pragma unroll
    for (int j = 0; j < 8; ++j) acc[j] = ba;
    for (int k = 0; k < H2; ++k){
        float wa = W_a[k*A + a];
        const float4 u0 = *(const float4*)&wss2[k][nh*8];
        const float4 u1 = *(const float4*)&wss2[k][nh*8 + 4];
        acc[0] += u0.x*wa; acc[1] += u0.y*wa; acc[2] += u0.z*wa; acc[3] += u0.w*wa;
        acc[4] += u1.x*wa; acc[5] += u1.y*wa; acc[6] += u1.z*wa; acc[7] += u1.w*wa;
    }
    float* dst = ws_aT + ((size_t)(b*A + a))*SW + n0 + nh*8;
    #pragma unroll
    for (int j = 0; j < 8; ++j) dst[j] = acc[j];
}

// ---------------- Wf = W_rc @ W1_top ; bf ; bconst ----------------
__global__ __launch_bounds__(256) void k_wf(
    const float* __restrict__ W_rc, const float* __restrict__ b_rc,
    const float* __restrict__ W1, const float* __restrict__ b1,
    const float* __restrict__ W_cc,
    float* __restrict__ Wf, float* __restrict__ bf, float* __restrict__ bconst)
{
    __shared__ float wrc[4][512];
    int j = blockIdx.x, tid = threadIdx.x;
    if (j < 256){
        for (int i = tid; i < 2048; i += 256){
            int kk = i >> 9, r = i & 511;
            wrc[kk][r] = W_rc[((size_t)(j*4 + kk))*H2 + r];
        }
        __syncthreads();
        float a0=0,a1=0,a2=0,a3=0;
        for (int r = 0; r < 512; ++r){
            float w1 = W1[(size_t)r*Hf + tid];
            a0 += wrc[0][r]*w1; a1 += wrc[1][r]*w1; a2 += wrc[2][r]*w1; a3 += wrc[3][r]*w1;
        }
        Wf[((size_t)(j*4+0))*Hf + tid] = a0;
        Wf[((size_t)(j*4+1))*Hf + tid] = a1;
        Wf[((size_t)(j*4+2))*Hf + tid] = a2;
        Wf[((size_t)(j*4+3))*Hf + tid] = a3;
    } else {
        float acc = b1[tid];
        for (int r = 0; r < 512; ++r) acc += b_rc[r]*W1[(size_t)r*Hf + tid];
        bf[tid] = acc;
        if (tid < 128){
            float a = 0.f;
            for (int c = 0; c < H2; ++c) a += b_rc[c]*W_cc[(size_t)(F+c)*F + tid];
            bconst[tid] = a;
        }
    }
}

// ---------------- WRCC = W_rc @ W_cc_bot ----------------
__global__ __launch_bounds__(128) void k_wrcc(
    const float* __restrict__ W_rc, const float* __restrict__ W_cc, float* __restrict__ WRCC)
{
    __shared__ float wr[512];
    int d = blockIdx.x, f = threadIdx.x;
    for (int i = f; i < 512; i += 128) wr[i] = W_rc[(size_t)d*H2 + i];
    __syncthreads();
    float a = 0.f;
    for (int c = 0; c < H2; ++c) a += wr[c]*W_cc[(size_t)(F+c)*F + f];
    WRCC[(size_t)d*F + f] = a;
}

// ---------------- embx ----------------
__global__ __launch_bounds__(128) void k_embx(
    const int* __restrict__ summary, const float* __restrict__ emb,
    const float* __restrict__ W_cc, const float* __restrict__ b_cc,
    float* __restrict__ embx)
{
    __shared__ float er[128];
    int t = blockIdx.x, b = blockIdx.y, f = threadIdx.x;
    int tok = summary[b*T + t];
    er[f] = emb[(size_t)tok*F + f];
    __syncthreads();
    float a = b_cc[f];
    for (int k = 0; k < F; ++k) a += er[k]*W_cc[(size_t)k*F + f];
    embx[((size_t)t*B + b)*F + f] = a;
}

// ---------------- bf16 pack kernels ----------------
__global__ __launch_bounds__(1024) void k_packw2(
    const float* __restrict__ W2, unsigned* __restrict__ W2h)
{
    size_t idx = (size_t)blockIdx.x*1024 + threadIdx.x;
    int rp = (int)(idx >> 15), v = (int)(idx & 32767);
    float lo = (v < VP1) ? W2[(size_t)(2*rp)*VP1 + v] : 0.f;
    float hi = (v < VP1) ? W2[(size_t)(2*rp+1)*VP1 + v] : 0.f;
    W2h[idx] = bfr(lo) | (bfr(hi) << 16);
}
__global__ __launch_bounds__(1024) void k_packws(
    const float* __restrict__ ws, unsigned* __restrict__ wsh)
{
    size_t idx = (size_t)blockIdx.x*1024 + threadIdx.x;
    int b = (int)(idx >> 18), r = (int)(idx & 262143);
    int np = r >> 9, d = r & 511;
    float lo = ws[((size_t)b*SW + 2*np)*H2 + d];
    float hi = ws[((size_t)b*SW + 2*np+1)*H2 + d];
    wsh[idx] = bfr(lo) | (bfr(hi) << 16);
}
__global__ __launch_bounds__(1024) void k_packwsa(
    const float* __restrict__ ws_aT, unsigned* __restrict__ ws_aTh)
{
    size_t idx = (size_t)blockIdx.x*1024 + threadIdx.x;
    int b = (int)(idx >> 16), r = (int)(idx & 65535);
    int ap = r >> 10, n = r & 1023;
    float lo = ws_aT[((size_t)b*A + 2*ap)*SW + n];
    float hi = ws_aT[((size_t)b*A + 2*ap+1)*SW + n];
    ws_aTh[idx] = bfr(lo) | (bfr(hi) << 16);
}
__global__ __launch_bounds__(1024) void k_packwg(
    const float* __restrict__ Wx, const float* __restrict__ Wh,
    unsigned* __restrict__ wgh)
{
    size_t idx = (size_t)blockIdx.x*1024 + threadIdx.x;
    int kp = (int)(idx >> 11), cg = (int)(idx & 2047);
    int k0 = 2*kp, k1 = 2*kp + 1;
    float lo = (k0 < F) ? Wx[(size_t)k0*2048 + cg] : Wh[(size_t)(k0-F)*2048 + cg];
    float hi = (k1 < F) ? Wx[(size_t)k1*2048 + cg] : Wh[(size_t)(k1-F)*2048 + cg];
    wgh[idx] = bfr(lo) | (bfr(hi) << 16);
}

// ---------------- persistent time-loop kernel (512 threads, 3 barriers/step, TE-truncated) ----------------
__global__ __launch_bounds__(512, 2) void k_persist(
    const float* __restrict__ ss,
    const int* __restrict__ text_length, const int* __restrict__ summary,
    const int* __restrict__ sumlen, const float* __restrict__ state,
    const unsigned* __restrict__ wgh, const float* __restrict__ b_lstm,
    const float* __restrict__ W_a, const float* __restrict__ v_a,
    const float* __restrict__ W1, const float* __restrict__ b2,
    const unsigned* __restrict__ W2h, const unsigned* __restrict__ wsh,
    const unsigned* __restrict__ ws_aTh,
    const float* __restrict__ Wf, const float* __restrict__ bf,
    const float* __restrict__ WRCC, const float* __restrict__ bconst,
    const float* __restrict__ embx,
    float* xR, float* outR, float* hidR,
    unsigned* wopartH, unsigned* PpkR, float* ZpartR, float* asumR,
    float* m2R, float* s2R, float* tgtlogR, float* covlpR,
    float* d_out, unsigned* cnt)
{
    __shared__ unsigned W2L[16384];   // 64 KB
    __shared__ unsigned wsaL[4096];   // 16 KB
    __shared__ float BIG[15552];
    __shared__ float redS[576];
    __shared__ float red2[528];
    __shared__ float wo_l[128];
    __shared__ float wac_l[128], vas_l[128], b2_l[128];
    __shared__ float expU_l[64], cov_l[64];
    __shared__ float c_l[128];
    __shared__ float gsum[528];
    __shared__ float asum_l[32];
    __shared__ float mred[136], sred[136], msc2[16];
    __shared__ float loss_l[16];
    __shared__ float Zsh;
    __shared__ int tl_l[32], sumlen_l[16], tgt_l[16];

    const int blk = blockIdx.x, tid = threadIdx.x;
    const int b_role = blk >> 4, sl = blk & 15;
    unsigned* arr = cnt;
    unsigned* rel = cnt + 8192;

    const int vl = tid & 127, rq = tid >> 7;        // logits
    const int n3 = tid & 63, aq = tid >> 6;         // scores
    const int cc = tid & 31, kg = tid >> 5;         // gates

    unsigned wsrN[32];
    #pragma unroll
    for (int j = 0; j < 32; ++j)
        wsrN[j] = wsh[((size_t)b_role*512 + sl*32 + j)*512 + tid];
    unsigned wgr[20];
    if (blk < 64){
        const int CGg = (cc >> 3)*512 + blk*8 + (cc & 7);
        #pragma unroll
        for (int j = 0; j < 20; ++j)
            wgr[j] = wgh[(size_t)(kg*20 + j)*2048 + CGg];
    }
    #pragma unroll
    for (int q = 0; q < 32; ++q){
        int i = q*512 + tid;
        W2L[i] = W2h[(size_t)(i >> 7)*32768 + blk*128 + (i & 127)];
    }
    #pragma unroll
    for (int q = 0; q < 8; ++q){
        int i = q*512 + tid;
        wsaL[i] = ws_aTh[((size_t)(b_role*64 + (i >> 6)))*1024 + sl*64 + (i & 63)];
    }

    if (tid < 128){
        wac_l[tid] = W_a[(size_t)(2*H2)*A + tid];
        vas_l[tid] = v_a[tid];
        int v2 = blk*128 + tid;
        b2_l[tid] = (v2 < VP1) ? b2[v2] : 0.f;
    }
    if (tid < 32) tl_l[tid] = text_length[b_role*S + tid];
    if (tid < 16){ sumlen_l[tid] = sumlen[tid]; loss_l[tid] = 0.f; }
    if (tid < 64) cov_l[tid] = 0.f;
    if (blk < 64 && tid < 128){
        int b = tid >> 3, c = tid & 7;
        c_l[tid] = state[(size_t)b*2*H2 + H2 + blk*8 + c];
    }
    __syncthreads();

    // Truncated horizon: steps t >= max(sumlen)-1 contribute zero to all losses.
    int maxsl = 2;
    #pragma unroll
    for (int i = 0; i < 16; ++i) maxsl = max(maxsl, sumlen_l[i]);
    const int TE = maxsl - 1;          // run t = 0..TE (t==TE = pipeline tail only)

    unsigned gen = 0;
    for (int t = 0; t <= TE; ++t){
        // ======== Phase A: cov/covloss(t-1) ; loss-merge(t-2) [blk255] ; gates(t) [blk<64] ========
        if (t >= 1){
            float invZ = frcp(Zsh);
            if (tid < 64){
                float at = expU_l[tid]*invZ;
                float clp = fminf(cov_l[tid], at);
                float vm1 = (sumlen_l[b_role] - t > 0) ? 1.f : 0.f;
                cov_l[tid] += at*vm1;
                float s = clp;
                s += __shfl_xor(s, 1);  s += __shfl_xor(s, 2);
                s += __shfl_xor(s, 4);  s += __shfl_xor(s, 8);
                s += __shfl_xor(s, 16); s += __shfl_xor(s, 32);
                if (tid == 0) ast(&covlpR[(size_t)(t-1)*256 + b_role*16 + sl], s);
            }
        }
        if (t >= 2 && blk == 255 && tid < 256){
            int tf = t - 2;
            int bb = tid >> 4, g = tid & 15;
            float mv[16];
            float m = -1e30f;
            #pragma unroll
            for (int j = 0; j < 16; ++j){
                mv[j] = m2R[(size_t)tf*B*256 + bb*256 + g + j*16];
                m = fmaxf(m, mv[j]);
            }
            #pragma unroll
            for (int off = 1; off < 16; off <<= 1) m = fmaxf(m, __shfl_xor(m, off, 16));
            float s = 0.f;
            #pragma unroll
            for (int j = 0; j < 16; ++j)
                s += s2R[(size_t)tf*B*256 + bb*256 + g + j*16]*__expf(mv[j]-m);
            #pragma unroll
            for (int off = 1; off < 16; off <<= 1) s += __shfl_xor(s, off, 16);
            if (g == 0){
                float cl = 0.f;
                for (int q = 0; q < 16; ++q) cl += covlpR[(size_t)tf*256 + bb*16 + q];
                float tlg = tgtlogR[(size_t)tf*16 + bb];
                float logp = tlg - m - __logf(s);
                float vld = (sumlen_l[bb] - tf - 1 > 0) ? 1.f : 0.f;
                loss_l[bb] += vld*(-logp + cl);
            }
        }
        if (t < TE && blk < 64){
            float* xh = BIG;
            float* outloc = BIG + 14336;
            float* waL = BIG + 14464;
            {
                int i2 = tid*2;
                waL[i2]   = W_a[(size_t)(H2 + blk*8 + (i2 >> 7))*A + (i2 & 127)];
                waL[i2+1] = W_a[(size_t)(H2 + blk*8 + ((i2+1) >> 7))*A + ((i2+1) & 127)];
            }
            const float* xb0 = xR + (size_t)t*B*F;
            const float* hb0 = outR + (size_t)(t > 0 ? t-1 : 0)*B*H2;
            #pragma unroll
            for (int q = 0; q < 20; ++q){
                int i = q*512 + tid;
                int b = i/640, k = i - b*640;
                float v;
                if (k < F) v = xb0[b*F + k];
                else if (t == 0) v = state[(size_t)b*2*H2 + (k - F)];
                else v = hb0[b*H2 + (k - F)] * ((sumlen_l[b] - t > 0) ? 1.f : 0.f);
                xh[i] = v;
            }
            __syncthreads();
            for (int b = 0; b < 16; ++b){
                const float* xb = &BIG[b*640 + kg*40];
                float s0 = 0.f, s1 = 0.f;
                #pragma unroll
                for (int j = 0; j < 20; ++j){
                    unsigned wu = wgr[j];
                    s0 = fmaf(xb[2*j],   blo(wu), s0);
                    s1 = fmaf(xb[2*j+1], bhi(wu), s1);
                }
                float p = s0 + s1;
                p += __shfl_xor(p, 32);
                if ((kg & 1) == 0)
                    BIG[10240 + (b*8 + (kg >> 1))*32 + cc] = p;
            }
            __syncthreads();
            {
                int b = tid >> 5, c2 = tid & 31;
                float s = 0.f;
                #pragma unroll
                for (int q = 0; q < 8; ++q) s += BIG[10240 + (b*8 + q)*32 + c2];
                gsum[b*33 + c2] = s;
            }
            __syncthreads();
            if (tid < 128){
                int b = tid >> 3, c = tid & 7, col = blk*8 + c;
                float gi = gsum[b*33 + c]      + b_lstm[col];
                float gf = gsum[b*33 + 8 + c]  + b_lstm[H2 + col];
                float gg = gsum[b*33 + 16 + c] + b_lstm[2*H2 + col];
                float go = gsum[b*33 + 24 + c] + b_lstm[3*H2 + col];
                float cold = c_l[tid];
                float cn = fsigm(gf)*cold + fsigm(gi)*ftanh_(gg);
                float o = fsigm(go)*ftanh_(cn);
                float valid = (sumlen_l[b] - t - 1 > 0) ? 1.f : 0.f;
                c_l[tid] = cn*valid;
                outloc[tid] = o;
                ast(&outR[(size_t)t*B*H2 + b*H2 + col], o);
            }
            __syncthreads();
            {
                int o2 = tid*2;
                int b = o2 >> 6, ap0 = o2 & 63;
                #pragma unroll
                for (int w = 0; w < 2; ++w){
                    int ap = ap0 + w, a0 = ap*2;
                    float acc0 = 0.f, acc1 = 0.f;
                    #pragma unroll
                    for (int j = 0; j < 8; ++j){
                        float ov = outloc[b*8 + j];
                        acc0 = fmaf(ov, waL[j*128 + a0],     acc0);
                        acc1 = fmaf(ov, waL[j*128 + a0 + 1], acc1);
                    }
                    astu(&wopartH[(size_t)t*65536 + blk*1024 + b*64 + ap],
                         bfr(acc0) | (bfr(acc1) << 16));
                }
            }
        }
        gen++; gbar(arr, rel, gen);

        // ======== Phase B: hidL prefetch (t>=1) ; wo-reduce + scores + P (t<TE) ========
        if (t >= 1){
            float* hidL = BIG + 2560;
            if (tid < 16){ int tok = summary[tid*T + t]; tgt_l[tid] = (tok == -1) ? V : tok; }
            #pragma unroll
            for (int q = 0; q < 8; ++q){
                int idx = q*512 + tid;
                int r = idx >> 4, b = idx & 15;
                hidL[b*264 + r] = hidR[(size_t)(t-1)*B*Hf + idx];
            }
        }
        if (t < TE){
            gsum[tid] = outR[(size_t)t*B*H2 + b_role*H2 + tid];
            {
                int ap = tid & 63, grp = tid >> 6;
                const unsigned* wp = wopartH + (size_t)t*65536 + (size_t)(grp*8)*1024
                                     + b_role*64 + ap;
                float lo = 0.f, hi = 0.f;
                #pragma unroll
                for (int q = 0; q < 8; ++q){
                    unsigned u = wp[(size_t)q*1024];
                    lo += blo(u); hi += bhi(u);
                }
                red2[ap*8 + grp] = lo;
                redS[ap*8 + grp] = hi;
            }
            __syncthreads();
            if (tid < 64){
                float lo = 0.f, hi = 0.f;
                #pragma unroll
                for (int q = 0; q < 8; ++q){ lo += red2[tid*8+q]; hi += redS[tid*8+q]; }
                wo_l[tid*2] = lo; wo_l[tid*2+1] = hi;
            }
            __syncthreads();
            {
                float cv = cov_l[n3];
                float acc = 0.f;
                #pragma unroll
                for (int i = 0; i < 8; ++i){
                    unsigned u = wsaL[(aq*8 + i)*64 + n3];
                    int a0 = aq*16 + 2*i;
                    acc = fmaf(ftanh_(blo(u) + wo_l[a0] + cv*wac_l[a0]), vas_l[a0], acc);
                    acc = fmaf(ftanh_(bhi(u) + wo_l[a0+1] + cv*wac_l[a0+1]), vas_l[a0+1], acc);
                }
                redS[aq*72 + n3] = acc;
            }
            __syncthreads();
            if (tid < 64){
                float s = 0.f;
                #pragma unroll
                for (int q = 0; q < 8; ++q) s += redS[q*72 + tid];
                int nn = sl*64 + tid;
                float sc = ((nn & 31) < tl_l[nn >> 5]) ? s : -1e9f;
                float e = __expf(sc);
                expU_l[tid] = e;
                float h = e;
                h += __shfl_xor(h, 1);  h += __shfl_xor(h, 2);
                h += __shfl_xor(h, 4);  h += __shfl_xor(h, 8);
                h += __shfl_xor(h, 16);
                float other = __shfl_xor(h, 32);
                if (tid == 0){
                    ast(&asumR[(size_t)t*512 + b_role*32 + sl*2 + 0], h);
                    ast(&asumR[(size_t)t*512 + b_role*32 + sl*2 + 1], other);
                    ast(&ZpartR[(size_t)t*256 + b_role*16 + sl], h + other);
                }
            }
            __syncthreads();
            {
                float p = 0.f;
                #pragma unroll
                for (int j = 0; j < 32; ++j){
                    unsigned u = wsrN[j];
                    p = fmaf(expU_l[2*j],   blo(u), p);
                    p = fmaf(expU_l[2*j+1], bhi(u), p);
                }
                float pnb = __shfl_xor(p, 1);
                if (!(tid & 1))
                    astu(&PpkR[((size_t)t*256 + blk)*256 + (tid >> 1)],
                         bfr(p) | (bfr(pnb) << 16));
            }
        }
        gen++; gbar(arr, rel, gen);

        // ======== Phase C: combine->c4 + hid/x (t<TE) ; logits(t-1) (t>=1) ========
        {
            float* c4l  = BIG;            // [0,1024)
            float* OL   = gsum;           // prefetched in B
            float* redd = BIG + 1536;     // [1536,2048)
            float* hidL = BIG + 2560;     // prefetched in B
            float* parts = BIG + 6784;    // [6784,15488)
            float* logitl = parts;
            if (t < TE){
                if (tid < 16) mred[tid] = ZpartR[(size_t)t*256 + b_role*16 + tid];
                if (tid >= 32 && tid < 64) asum_l[tid-32] = asumR[(size_t)t*512 + b_role*32 + (tid-32)];
                if (tid < 256){
                    float lo = 0.f, hi = 0.f;
                    const unsigned* pp = PpkR + ((size_t)t*256 + b_role*16)*256 + tid;
                    #pragma unroll
                    for (int q = 0; q < 16; ++q){
                        unsigned u = pp[(size_t)q*256];
                        lo += blo(u); hi += bhi(u);
                    }
                    c4l[2*tid] = lo; c4l[2*tid+1] = hi;
                }
            }
            __syncthreads();
            if (t < TE){
                float zloc = 0.f;
                #pragma unroll
                for (int i = 0; i < 16; ++i) zloc += mred[i];
                if (tid == 0) Zsh = zloc;
                float invZ = frcp(zloc);
                float sent = 0.f;
                const float* ssb = ss + (size_t)(b_role*S)*H2 + tid;
                #pragma unroll 4
                for (int s2 = 0; s2 < 32; ++s2)
                    sent = fmaf(asum_l[s2], ssb[(size_t)s2*H2], sent);
                float w = c4l[tid]*invZ;
                c4l[tid] = w;
                c4l[512 + tid] = sent*invZ;
            }
            __syncthreads();
            if (t >= 1){
                unsigned wreg[32];
                #pragma unroll
                for (int i = 0; i < 32; ++i) wreg[i] = W2L[(rq*32 + i)*128 + vl];
                for (int b = 0; b < 16; ++b){
                    const float2* hb2 = (const float2*)&hidL[b*264 + rq*64];
                    float a0 = 0.f, a1 = 0.f;
                    #pragma unroll
                    for (int i = 0; i < 32; ++i){
                        unsigned u = wreg[i];
                        float2 h = hb2[i];
                        a0 = fmaf(h.x, blo(u), a0);
                        a1 = fmaf(h.y, bhi(u), a1);
                    }
                    parts[rq*2176 + vl*17 + b] = a0 + a1;
                }
            }
            if (t < TE && sl < 12){
                int cl = tid & 31, kq = tid >> 5;
                if (sl < 8){
                    int col = sl*32 + cl;
                    float acc = 0.f;
                    const float* wp = Wf + (size_t)(kq*64)*Hf + col;
                    #pragma unroll 4
                    for (int i = 0; i < 64; ++i)
                        acc = fmaf(c4l[kq*64+i], wp[(size_t)i*Hf], acc);
                    const float* w1p = W1 + (size_t)(H2 + kq*32)*Hf + col;
                    #pragma unroll 4
                    for (int i = 0; i < 32; ++i)
                        acc = fmaf(OL[kq*32+i], w1p[(size_t)i*Hf], acc);
                    redd[kq*32 + cl] = acc;
                } else {
                    int f = (sl-8)*32 + cl;
                    float acc = 0.f;
                    const float* wp = WRCC + (size_t)(kq*64)*F + f;
                    #pragma unroll 4
                    for (int i = 0; i < 64; ++i)
                        acc = fmaf(c4l[kq*64+i], wp[(size_t)i*F], acc);
                    redd[kq*32 + cl] = acc;
                }
            }
            __syncthreads();
            if (t < TE && sl < 12 && tid < 32){
                if (sl < 8){
                    float z = 0.f;
                    #pragma unroll
                    for (int q = 0; q < 16; ++q) z += redd[q*32 + tid];
                    z += bf[sl*32 + tid];
                    ast(&hidR[(size_t)t*B*Hf + (sl*32 + tid)*16 + b_role], fmaxf(z, 0.f));
                } else {
                    int f2 = (sl-8)*32 + tid;
                    float z = 0.f;
                    #pragma unroll
                    for (int q = 0; q < 16; ++q) z += redd[q*32 + tid];
                    float vld = (sumlen_l[b_role] - t - 1 > 0) ? 1.f : 0.f;
                    float xv = embx[((size_t)(t+1)*B + b_role)*F + f2] + vld*(z + bconst[f2]);
                    ast(&xR[(size_t)(t+1)*B*F + b_role*F + f2], xv);
                }
            }
            if (t >= 1){
                #pragma unroll
                for (int j = 0; j < 4; ++j){
                    int idx = tid*4 + j;
                    int vl2 = idx >> 4, bb = idx & 15;
                    float s = parts[0*2176 + vl2*17 + bb]
                            + parts[1*2176 + vl2*17 + bb]
                            + parts[2*2176 + vl2*17 + bb]
                            + parts[3*2176 + vl2*17 + bb];
                    int v2 = blk*128 + vl2;
                    float lg = (v2 < VP1) ? (s + b2_l[vl2]) : -1e30f;
                    if (v2 < VP1 && v2 == tgt_l[bb])
                        ast(&tgtlogR[(size_t)(t-1)*16 + bb], lg);
                    logitl[vl2*17 + bb] = lg;
                }
                __syncthreads();
                if (tid < 128){
                    int b2i = tid & 15, grp = tid >> 4;
                    float m = -1e30f;
                    #pragma unroll
                    for (int i = 0; i < 16; ++i) m = fmaxf(m, logitl[(grp*16+i)*17 + b2i]);
                    mred[grp*17 + b2i] = m;
                }
                __syncthreads();
                if (tid < 16){
                    float m = -1e30f;
                    #pragma unroll
                    for (int q = 0; q < 8; ++q) m = fmaxf(m, mred[q*17 + tid]);
                    msc2[tid] = m;
                }
                __syncthreads();
                if (tid < 128){
                    int b2i = tid & 15, grp = tid >> 4;
                    float Mb = msc2[b2i];
                    float s = 0.f;
                    #pragma unroll
                    for (int i = 0; i < 16; ++i) s += __expf(logitl[(grp*16+i)*17 + b2i] - Mb);
                    sred[grp*17 + b2i] = s;
                }
                __syncthreads();
                if (tid < 16){
                    float s = 0.f;
                    #pragma unroll
                    for (int q = 0; q < 8; ++q) s += sred[q*17 + tid];
                    ast(&m2R[(size_t)(t-1)*B*256 + tid*256 + blk], msc2[tid]);
                    ast(&s2R[(size_t)(t-1)*B*256 + tid*256 + blk], s);
                }
            }
        }
        gen++; gbar(arr, rel, gen);
    }

    // ======== epilogue: loss-merge(TE-1) + output [blk255] ========
    if (blk == 255 && tid < 256){
        int tf = TE - 1;
        int bb = tid >> 4, g = tid & 15;
        float mv[16];
        float m = -1e30f;
        #pragma unroll
        for (int j = 0; j < 16; ++j){
            mv[j] = m2R[(size_t)tf*B*256 + bb*256 + g + j*16];
            m = fmaxf(m, mv[j]);
        }
        #pragma unroll
        for (int off = 1; off < 16; off <<= 1) m = fmaxf(m, __shfl_xor(m, off, 16));
        float s = 0.f;
        #pragma unroll
        for (int j = 0; j < 16; ++j)
            s += s2R[(size_t)tf*B*256 + bb*256 + g + j*16]*__expf(mv[j]-m);
        #pragma unroll
        for (int off = 1; off < 16; off <<= 1) s += __shfl_xor(s, off, 16);
        if (g == 0){
            float cl = 0.f;
            for (int q = 0; q < 16; ++q) cl += covlpR[(size_t)tf*256 + bb*16 + q];
            float tlg = tgtlogR[(size_t)tf*16 + bb];
            float logp = tlg - m - __logf(s);
            float vld = (sumlen_l[bb] - tf - 1 > 0) ? 1.f : 0.f;
            loss_l[bb] += vld*(-logp + cl);
            d_out[bb] = loss_l[bb] / ((float)sumlen_l[bb] - 1.f);
        }
    }
}

extern "C" void kernel_launch(void* const* d_in, const int* in_sizes, int n_in,
                              void* d_out, int out_size, void* d_ws, size_t ws_size,
                              hipStream_t stream) {
    const float* text_states = (const float*)d_in[0];
    const float* sent_states = (const float*)d_in[1];
    const int*   text_length = (const int*)d_in[2];
    const float* state       = (const float*)d_in[3];
    const int*   summary     = (const int*)d_in[4];
    const int*   sumlen      = (const int*)d_in[5];
    const float* emb    = (const float*)d_in[6];
    const float* W_cc   = (const float*)d_in[7];
    const float* b_cc   = (const float*)d_in[8];
    const float* Wx     = (const float*)d_in[9];
    const float* Wh     = (const float*)d_in[10];
    const float* b_lstm = (const float*)d_in[11];
    const float* W_a    = (const float*)d_in[12];
    const float* b_a    = (const float*)d_in[13];
    const float* v_a    = (const float*)d_in[14];
    const float* W_rc   = (const float*)d_in[15];
    const float* b_rc   = (const float*)d_in[16];
    const float* W1     = (const float*)d_in[17];
    const float* b1     = (const float*)d_in[18];
    const float* W2     = (const float*)d_in[19];
    const float* b2     = (const float*)d_in[20];
    float* out = (float*)d_out;

    float* p = (float*)d_ws;
    float* ws_aT   = p; p += (size_t)B*A*SW;
    float* Wf      = p; p += (size_t)1024*Hf;
    float* bfv     = p; p += Hf;
    float* WRCC    = p; p += (size_t)1024*F;
    float* bconst  = p; p += F;
    float* embx    = p; p += (size_t)T*B*F;
    float* xR      = p; p += (size_t)(NSTEP+1)*B*F;
    float* outR    = p; p += (size_t)(NSTEP+1)*B*H2;
    float* hidR    = p; p += (size_t)(NSTEP+1)*B*Hf;
    float* ZpartR  = p; p += (size_t)(NSTEP+1)*256;
    float* asumR   = p; p += (size_t)(NSTEP+1)*512;
    float* m2R     = p; p += (size_t)(NSTEP+1)*B*256;
    float* s2R     = p; p += (size_t)(NSTEP+1)*B*256;
    float* tgtlogR = p; p += (size_t)(NSTEP+1)*16;
    float* covlpR  = p; p += (size_t)(NSTEP+1)*256;
    unsigned* cnt  = (unsigned*)p; p += 8704;
    unsigned* W2h    = (unsigned*)p; p += (size_t)128*32768;
    unsigned* wsh    = (unsigned*)p; p += (size_t)16*512*512;
    unsigned* ws_aTh = (unsigned*)p; p += (size_t)16*64*1024;
    unsigned* wgh    = (unsigned*)p; p += (size_t)320*2048;
    unsigned* wopartH= (unsigned*)p; p += (size_t)NSTEP*65536;
    unsigned* PpkR   = (unsigned*)p; p += (size_t)NSTEP*256*256;

    k_init0<<<17, 256, 0, stream>>>(emb, W_cc, b_cc, summary, xR, cnt);
    k_wsa<<<dim3(B, 64), 256, 0, stream>>>(text_states, W_a, b_a, ws_aT);
    k_wf<<<257, 256, 0, stream>>>(W_rc, b_rc, W1, b1, W_cc, Wf, bfv, bconst);
    k_wrcc<<<1024, 128, 0, stream>>>(W_rc, W_cc, WRCC);
    k_embx<<<dim3(T, B), 128, 0, stream>>>(summary, emb, W_cc, b_cc, embx);
    k_packw2<<<4096, 1024, 0, stream>>>(W2, W2h);
    k_packws<<<4096, 1024, 0, stream>>>(text_states, wsh);
    k_packwsa<<<1024, 1024, 0, stream>>>(ws_aT, ws_aTh);
    k_packwg<<<640, 1024, 0, stream>>>(Wx, Wh, wgh);
    k_persist<<<NBLK, 512, 0, stream>>>(
        sent_states, text_length, summary, sumlen, state,
        wgh, b_lstm, W_a, v_a, W1, b2,
        W2h, wsh, ws_aTh, Wf, bfv, WRCC, bconst, embx,
        xR, outR, hidR, wopartH, PpkR, ZpartR, asumR,
        m2R, s2R, tgtlogR, covlpR, out, cnt);
}